// Round 7
// baseline (818.220 us; speedup 1.0000x reference)
//
#include <hip/hip_runtime.h>
#include <math.h>

#define TPB 256
typedef unsigned short u16;
typedef _Float16 v8h __attribute__((ext_vector_type(8)));
typedef float v4f __attribute__((ext_vector_type(4)));

__device__ __forceinline__ u16 f2h(float v) {
    return __builtin_bit_cast(u16, (_Float16)v);
}
__device__ __forceinline__ float h2f(u16 v) {
    return (float)__builtin_bit_cast(_Float16, v);
}

typedef const __attribute__((address_space(1))) unsigned int* gp1_t;
typedef __attribute__((address_space(3))) unsigned int* lp3_t;
__device__ __forceinline__ void gload_lds16(const void* g, void* l) {
    __builtin_amdgcn_global_load_lds((gp1_t)g, (lp3_t)l, 16, 0, 0);
}

// ---------------------------------------------------------------------------
// weight cast + permute: OIHW fp32 -> [co][ky*3+kx][ci] f16
// ---------------------------------------------------------------------------
__global__ __launch_bounds__(256) void cast_perm_k(
    const float* __restrict__ src, u16* __restrict__ dst, int Cout, int Cin)
{
    int i = blockIdx.x * TPB + threadIdx.x;
    int total = Cout * Cin * 9;
    if (i >= total) return;
    int ci = i % Cin, rest = i / Cin;
    int w = rest % 9, co = rest / 9;
    dst[i] = f2h(src[(co * Cin + ci) * 9 + w]);
}

__global__ __launch_bounds__(256) void zero4_k(uint4* __restrict__ p, int n)
{
    int i = blockIdx.x * TPB + threadIdx.x;
    if (i < n) p[i] = (uint4){0u, 0u, 0u, 0u};
}

// ---------------------------------------------------------------------------
// Implicit-GEMM conv from HALO'ed NHWC f16 act ((H+2)x(W+2)xC per image,
// interior pixel (y,x) at ((y+1)*Wpad+(x+1))*C, halo cells zero -> no bounds
// predication -> every B row-chunk is an unconditional 16B global_load_lds.
// Double-buffered LDS; loads for step k+1 issued right after the barrier,
// drained by the next iteration's vmcnt(0) -> fetch overlaps MFMA.
// XOR swizzle c ^ ((row>>1)&3) keeps DMA lane-contiguous and ds_read_b128
// 2-way aliased only (free). Block = 4 waves, wave tile 64x64 (4x4 mfma
// 16x16x32 f16); block tile (WGM*64)x(WGN*64).
// DEFORM=0: epilogue stores fp32 NCHW C (+bias,relu).
// DEFORM=1: off-conv + bilinear deform fused, honoring the torch-faithful
//   reshape (b,2c,h,w)->(b*c,h*w,2): flat f = m*HW + pos maps to channel
//   c=m>>1, target pixel p=(m&1)*HW/2 + posE/2, component d=pos&1 (posE=
//   pos&~1). Columns pos/pos+1 sit in an even/odd lane pair -> one
//   __shfl_xor(1) exchange completes each (dy,dx); even lanes process acc
//   rows 0-1, odd lanes rows 2-3 (disjoint, full coverage). Gather from the
//   SAME halo'ed input act, write deformed act f16.
// ---------------------------------------------------------------------------
template <int WGM, int WGN, int DEFORM>
__global__ __launch_bounds__(256) void gemm_impl_k(
    const u16* __restrict__ A, const u16* __restrict__ act, float* __restrict__ C,
    u16* __restrict__ outd, const float* __restrict__ bias,
    int M, int K, int Npix, int relu,
    int Cin, int CPWlog, int Wpad, int Wolog, int stride, size_t astride)
{
    constexpr int BM = WGM * 64, BN = WGN * 64;
    constexpr int ASLOTS = BM / 16, BSLOTS = BN / 16;
    constexpr int SLOTS = ASLOTS + BSLOTS, SPW = SLOTS / 4;
    __shared__ u16 lds[2][(BM + BN) * 32];
    const int t = threadIdx.x, lane = t & 63, wave = t >> 6;
    const int g = blockIdx.z;
    const int p0 = blockIdx.x * BN, m0 = blockIdx.y * BM;
    const u16* actg = act + (size_t)g * astride;
    const int Wo = 1 << Wolog;

    const u16* src[SPW];
#pragma unroll
    for (int i = 0; i < SPW; ++i) {
        int s = wave * SPW + i;
        if (s < ASLOTS) {
            int ch = s * 64 + lane, nr = ch >> 2, cst = ch & 3;
            int csrc = cst ^ ((nr >> 1) & 3);
            src[i] = A + (size_t)(m0 + nr) * K + csrc * 8;
        } else {
            int ch = (s - ASLOTS) * 64 + lane, nr = ch >> 2, cst = ch & 3;
            int csrc = cst ^ ((nr >> 1) & 3);
            int p = p0 + nr, oy = p >> Wolog, ox = p & (Wo - 1);
            src[i] = actg + (size_t)(oy * stride * Wpad + ox * stride) * Cin + csrc * 8;
        }
    }

    auto issue = [&](int kk, int buf) {
        int k0 = kk << 5;
        int w = kk >> CPWlog;
        int ci0 = (kk & ((1 << CPWlog) - 1)) << 5;
        int koff = (w / 3 * Wpad + w % 3) * Cin + ci0;
#pragma unroll
        for (int i = 0; i < SPW; ++i) {
            int s = wave * SPW + i;
            const u16* sp = src[i] + ((s < ASLOTS) ? k0 : koff);
            gload_lds16(sp, lds[buf] + s * 512);
        }
    };

    v4f acc[4][4];
#pragma unroll
    for (int mi = 0; mi < 4; ++mi)
#pragma unroll
        for (int ni = 0; ni < 4; ++ni) acc[mi][ni] = (v4f){0.f, 0.f, 0.f, 0.f};

    const int wm = wave % WGM, wn = wave / WGM;
    const int la = lane & 15, quad = lane >> 4;

    issue(0, 0);
    const int nk = K >> 5;
    for (int kk = 0; kk < nk; ++kk) {
        int buf = kk & 1;
        asm volatile("s_waitcnt vmcnt(0)\n\ts_barrier" ::: "memory");
        if (kk + 1 < nk) issue(kk + 1, buf ^ 1);
        const u16* Lb = lds[buf];
        v8h a[4], b[4];
#pragma unroll
        for (int mi = 0; mi < 4; ++mi) {
            int r = wm * 64 + mi * 16 + la;
            a[mi] = *(const v8h*)(Lb + (r * 4 + (quad ^ ((r >> 1) & 3))) * 8);
        }
#pragma unroll
        for (int ni = 0; ni < 4; ++ni) {
            int r = wn * 64 + ni * 16 + la;
            b[ni] = *(const v8h*)(Lb + BM * 32 + (r * 4 + (quad ^ ((r >> 1) & 3))) * 8);
        }
#pragma unroll
        for (int mi = 0; mi < 4; ++mi)
#pragma unroll
            for (int ni = 0; ni < 4; ++ni)
                acc[mi][ni] = __builtin_amdgcn_mfma_f32_16x16x32_f16(
                    a[mi], b[ni], acc[mi][ni], 0, 0, 0);
    }

    if (!DEFORM) {
        float* Cimg = C + (size_t)g * M * Npix;
#pragma unroll
        for (int mi = 0; mi < 4; ++mi) {
#pragma unroll
            for (int r = 0; r < 4; ++r) {
                int row = m0 + wm * 64 + mi * 16 + quad * 4 + r;
                float bv = bias ? bias[row] : 0.f;
#pragma unroll
                for (int ni = 0; ni < 4; ++ni) {
                    int col = p0 + wn * 64 + ni * 16 + la;
                    float v = acc[mi][ni][r] + bv;
                    if (relu) v = fmaxf(v, 0.f);
                    Cimg[(size_t)row * Npix + col] = v;
                }
            }
        }
    } else {
        u16* og = outd + (size_t)g * astride;
        const int HWh = Npix >> 1;
        const int Ho = Npix >> Wolog;
        const int odd = lane & 1;
#pragma unroll
        for (int mi = 0; mi < 4; ++mi) {
            int mbase = m0 + wm * 64 + mi * 16 + quad * 4;   // even
#pragma unroll
            for (int ni = 0; ni < 4; ++ni) {
                int pos = p0 + wn * 64 + ni * 16 + la;
                int posE = pos & ~1;
                float oth[4];
#pragma unroll
                for (int r = 0; r < 4; ++r)
                    oth[r] = __shfl_xor(acc[mi][ni][r], 1);
#pragma unroll
                for (int j = 0; j < 2; ++j) {
                    int r = odd * 2 + j;                      // even lane: 0,1; odd: 2,3
                    int m = mbase + r;
                    int c = m >> 1;
                    int p = (m & 1) * HWh + (posE >> 1);
                    float dy = odd ? oth[r] : acc[mi][ni][r];
                    float dx = odd ? acc[mi][ni][r] : oth[r];
                    int yy = p >> Wolog, xx = p & (Wo - 1);
                    float cy = fminf(fmaxf((float)yy + dy, 0.f), (float)(Ho - 1));
                    float cx = fminf(fmaxf((float)xx + dx, 0.f), (float)(Wo - 1));
                    float y0f = floorf(cy), x0f = floorf(cx);
                    float ty = cy - y0f, tx = cx - x0f;
                    int y0 = (int)y0f, y1 = (int)ceilf(cy);
                    int x0 = (int)x0f, x1 = (int)ceilf(cx);
                    float vlt = h2f(actg[((size_t)(y0 + 1) * Wpad + (x0 + 1)) * Cin + c]);
                    float vrt = h2f(actg[((size_t)(y1 + 1) * Wpad + (x0 + 1)) * Cin + c]);
                    float vlb = h2f(actg[((size_t)(y0 + 1) * Wpad + (x1 + 1)) * Cin + c]);
                    float vrb = h2f(actg[((size_t)(y1 + 1) * Wpad + (x1 + 1)) * Cin + c]);
                    float vt = ty * (vrt - vlt) + vlt;
                    float vb = ty * (vrb - vlb) + vlb;
                    og[((size_t)(yy + 1) * Wpad + (xx + 1)) * Cin + c] =
                        f2h(tx * (vb - vt) + vt);
                }
            }
        }
    }
}

// ---------------------------------------------------------------------------
// Direct 3x3 conv (conv11 only, Cin=1), fp32 NCHW out
// ---------------------------------------------------------------------------
template <int STRIDE>
__global__ __launch_bounds__(256) void conv3x3_k(
    const float* __restrict__ in, const float* __restrict__ wgt,
    const float* __restrict__ bias, float* __restrict__ out,
    int N, int Cin, int H, int W, int Cout_buf, int Ho, int Wo,
    int relu, int co_base)
{
    constexpr int IT = 15 * STRIDE + 3;
    __shared__ float tile[IT * IT];
    const int tid = threadIdx.x;
    const int tx = tid & 15, ty = tid >> 4;
    const int coutg = Cout_buf >> 2;
    const int n = blockIdx.z / coutg;
    const int cog = blockIdx.z - n * coutg;
    const int co0 = cog << 2;
    const int ox = (blockIdx.x << 4) + tx;
    const int oy = (blockIdx.y << 4) + ty;
    const int ix0 = (blockIdx.x << 4) * STRIDE - 1;
    const int iy0 = (blockIdx.y << 4) * STRIDE - 1;
    const float* inN = in + (size_t)n * Cin * H * W;
    float acc[4] = {0.f, 0.f, 0.f, 0.f};

    for (int ci = 0; ci < Cin; ++ci) {
        const float* plane = inN + (size_t)ci * H * W;
        __syncthreads();
        for (int i = tid; i < IT * IT; i += TPB) {
            int r = i / IT, c = i - r * IT;
            int yy = iy0 + r, xx = ix0 + c;
            float v = 0.f;
            if (yy >= 0 && yy < H && xx >= 0 && xx < W) v = plane[yy * W + xx];
            tile[i] = v;
        }
        __syncthreads();
        const int ly = ty * STRIDE, lx = tx * STRIDE;
        float nb[9];
#pragma unroll
        for (int ky = 0; ky < 3; ++ky)
#pragma unroll
            for (int kx = 0; kx < 3; ++kx)
                nb[ky * 3 + kx] = tile[(ly + ky) * IT + lx + kx];
        const float* wp = wgt + ((size_t)(co_base + co0) * Cin + ci) * 9;
#pragma unroll
        for (int j = 0; j < 4; ++j) {
            const float* w9 = wp + (size_t)j * Cin * 9;
            float a = acc[j];
#pragma unroll
            for (int k = 0; k < 9; ++k) a += nb[k] * w9[k];
            acc[j] = a;
        }
    }
#pragma unroll
    for (int j = 0; j < 4; ++j) {
        float v = acc[j];
        if (bias) v += bias[co_base + co0 + j];
        if (relu) v = fmaxf(v, 0.f);
        out[(((size_t)n * Cout_buf + (co0 + j)) * Ho + oy) * Wo + ox] = v;
    }
}

// ---------------------------------------------------------------------------
// BatchNorm
// ---------------------------------------------------------------------------
__global__ void zero_k(float* p, int n)
{
    int i = blockIdx.x * TPB + threadIdx.x;
    if (i < n) p[i] = 0.f;
}

__global__ __launch_bounds__(256) void bn_stats_k(
    const float* __restrict__ x, float* __restrict__ stats,
    int C, int HWlog, int NHW, int SPLIT)
{
    const int c = blockIdx.y, sb = blockIdx.x, tid = threadIdx.x;
    const int HWm = (1 << HWlog) - 1;
    float s = 0.f, s2 = 0.f;
    for (int i = sb * TPB + tid; i < NHW; i += SPLIT * TPB) {
        int nn = i >> HWlog, p = i & HWm;
        float v = x[(((size_t)nn * C + c) << HWlog) + p];
        s += v;
        s2 += v * v;
    }
    __shared__ float r1[TPB], r2[TPB];
    r1[tid] = s; r2[tid] = s2;
    __syncthreads();
    for (int d = TPB / 2; d > 0; d >>= 1) {
        if (tid < d) { r1[tid] += r1[tid + d]; r2[tid] += r2[tid + d]; }
        __syncthreads();
    }
    if (tid == 0) {
        atomicAdd(&stats[2 * c], r1[0]);
        atomicAdd(&stats[2 * c + 1], r2[0]);
    }
}

// in-place fp32 NCHW apply (last BN only)
__global__ __launch_bounds__(256) void bn_apply_k(
    float* __restrict__ x, const float* __restrict__ stats,
    const float* __restrict__ g, const float* __restrict__ b,
    int Cm1, int HWlog, float invcnt, int total)
{
    int idx = blockIdx.x * TPB + threadIdx.x;
    if (idx >= total) return;
    int c = (idx >> HWlog) & Cm1;
    float mean = stats[2 * c] * invcnt;
    float var  = fmaxf(stats[2 * c + 1] * invcnt - mean * mean, 0.f);
    float sc   = g[c] / sqrtf(var + 1e-5f);
    x[idx] = (x[idx] - mean) * sc + b[c];
}

// fused BN-apply + NCHW->halo'ed-NHWC transpose + f16 cast.
// grid (HW/64, C/32, N)
__global__ __launch_bounds__(256) void bn_apply_t_k(
    const float* __restrict__ x, const float* __restrict__ stats,
    const float* __restrict__ gamma, const float* __restrict__ beta,
    u16* __restrict__ out, int C, int HWlog, int Wlog, int Wpad,
    size_t ostride, float invcnt)
{
    __shared__ float tile[32 * 65];
    __shared__ float smean[32], ssc[32], sb2[32];
    int t = threadIdx.x;
    int img = blockIdx.z, c0 = blockIdx.y * 32, p0 = blockIdx.x * 64;
    if (t < 32) {
        int c = c0 + t;
        float mean = stats[2 * c] * invcnt;
        float var = fmaxf(stats[2 * c + 1] * invcnt - mean * mean, 0.f);
        smean[t] = mean;
        ssc[t] = gamma[c] / sqrtf(var + 1e-5f);
        sb2[t] = beta[c];
    }
    __syncthreads();
    const float* xi = x + (((size_t)img * C) << HWlog);
    u16* oi = out + (size_t)img * ostride;
    const int Wm1 = (1 << Wlog) - 1;
#pragma unroll
    for (int i = 0; i < 8; ++i) {
        int e = t + i * 256;
        int cl = e >> 6, pp = e & 63;
        float v = xi[(((size_t)(c0 + cl)) << HWlog) + p0 + pp];
        tile[cl * 65 + pp] = (v - smean[cl]) * ssc[cl] + sb2[cl];
    }
    __syncthreads();
#pragma unroll
    for (int i = 0; i < 8; ++i) {
        int e = t + i * 256;
        int cl = e & 31, pp = e >> 5;
        int p = p0 + pp, y = p >> Wlog, xx = p & Wm1;
        oi[((size_t)(y + 1) * Wpad + (xx + 1)) * C + c0 + cl] =
            f2h(tile[cl * 65 + pp]);
    }
}

// ---------------------------------------------------------------------------
__global__ __launch_bounds__(64) void gap_k(
    const float* __restrict__ x, float* __restrict__ pooled, int HW, float inv)
{
    int bc = blockIdx.x;
    float s = 0.f;
    for (int i = threadIdx.x; i < HW; i += 64) s += x[(size_t)bc * HW + i];
#pragma unroll
    for (int d = 32; d > 0; d >>= 1) s += __shfl_down(s, d);
    if (threadIdx.x == 0) pooled[bc] = s * inv;
}

__global__ __launch_bounds__(64) void fc_softmax_k(
    const float* __restrict__ pooled, const float* __restrict__ fw,
    const float* __restrict__ fb, float* __restrict__ outp)
{
    int n = blockIdx.x;
    __shared__ float logits[10];
    int k = threadIdx.x;
    if (k < 10) {
        float s = fb[k];
        const float* row = pooled + n * 128;
        const float* wr  = fw + k * 128;
        for (int c = 0; c < 128; ++c) s += row[c] * wr[c];
        logits[k] = s;
    }
    __syncthreads();
    if (k < 10) {
        float m = logits[0];
#pragma unroll
        for (int j = 1; j < 10; ++j) m = fmaxf(m, logits[j]);
        float den = 0.f;
#pragma unroll
        for (int j = 0; j < 10; ++j) den += expf(logits[j] - m);
        outp[n * 10 + k] = expf(logits[k] - m) / den;
    }
}

// ---------------------------------------------------------------------------
// Workspace (~143.9 MB, proven safe):
//   SCRATCH 16,777,216 f (64 MB)  -- fp32 conv outputs only
//   ACTB0   18,874,368 u16 (36 MB, halo'ed NHWC f16)
//   ACTB1   18,874,368 u16 (36 MB)
//   WBF + STATS/POOLED
// Halo'ed strides: AS1=130*130*32, AS2=66*66*64, AS3=66*66*128. Buffers are
// re-zeroed for each stage layout before reuse so halo cells stay 0.
// ---------------------------------------------------------------------------
extern "C" void kernel_launch(void* const* d_in, const int* in_sizes, int n_in,
                              void* d_out, int out_size, void* d_ws, size_t ws_size,
                              hipStream_t stream)
{
    const float* x     = (const float*)d_in[0];
    const float* c11w  = (const float*)d_in[1];
    const float* c11b  = (const float*)d_in[2];
    const float* bn11g = (const float*)d_in[3];
    const float* bn11b = (const float*)d_in[4];
    const float* o12w  = (const float*)d_in[5];
    const float* c12w  = (const float*)d_in[6];
    const float* c12b  = (const float*)d_in[7];
    const float* bn12g = (const float*)d_in[8];
    const float* bn12b = (const float*)d_in[9];
    const float* o21w  = (const float*)d_in[10];
    const float* c21w  = (const float*)d_in[11];
    const float* c21b  = (const float*)d_in[12];
    const float* bn21g = (const float*)d_in[13];
    const float* bn21b = (const float*)d_in[14];
    const float* o22w  = (const float*)d_in[15];
    const float* c22w  = (const float*)d_in[16];
    const float* c22b  = (const float*)d_in[17];
    const float* bn22g = (const float*)d_in[18];
    const float* bn22b = (const float*)d_in[19];
    const float* fcw   = (const float*)d_in[20];
    const float* fcb   = (const float*)d_in[21];
    float* outp = (float*)d_out;

    const int N = 32;
    float* ws      = (float*)d_ws;
    float* SCRATCH = ws;                          // 16,777,216 floats (64 MB)
    u16*   ACTB0   = (u16*)(ws + 16777216);       // 18,874,368 u16 (36 MB)
    u16*   ACTB1   = (u16*)(ws + 26214400);       // 18,874,368 u16 (36 MB)
    u16*   WBF     = (u16*)(ws + 35651584);       // 626,688 u16
    float* STATS   = ws + 35964928;               // 256
    float* POOLED  = STATS + 256;                 // 4096

    auto zero_region = [&](u16* p, size_t n_u16) {
        int n4 = (int)(n_u16 / 8);
        zero4_k<<<(n4 + TPB - 1) / TPB, TPB, 0, stream>>>((uint4*)p, n4);
    };
    // initial zero of both act buffers (stage-1 AS1 halos)
    zero_region(ACTB0, 2u * 18874368u);

    u16* wo12 = WBF + 0;
    u16* wc12 = WBF + 18432;
    u16* wo21 = WBF + 36864;
    u16* wc21 = WBF + 110592;
    u16* wo22 = WBF + 184320;
    u16* wc22 = WBF + 479232;
    auto cast = [&](const float* s, u16* d, int Cout, int Cin) {
        int n = Cout * Cin * 9;
        cast_perm_k<<<(n + TPB - 1) / TPB, TPB, 0, stream>>>(s, d, Cout, Cin);
    };
    cast(o12w, wo12, 64, 32);
    cast(c12w, wc12, 64, 32);
    cast(o21w, wo21, 128, 64);
    cast(c21w, wc21, 128, 64);
    cast(o22w, wo22, 256, 128);
    cast(c22w, wc22, 128, 128);

    // conv GEMM (fp32 NCHW out, bias+relu)
    auto gemm = [&](const u16* A, const u16* actb, float* Cp, const float* bias,
                    int M, int K, int Npix, int Cin, int CPWlog,
                    int Wpad, int Wolog, int stride, size_t astride) {
        if (M == 64) {
            dim3 g(Npix / 256, 1, N);
            gemm_impl_k<1, 4, 0><<<g, TPB, 0, stream>>>(A, actb, Cp, nullptr,
                bias, M, K, Npix, 1, Cin, CPWlog, Wpad, Wolog, stride, astride);
        } else {
            dim3 g(Npix / 128, M / 128, N);
            gemm_impl_k<2, 2, 0><<<g, TPB, 0, stream>>>(A, actb, Cp, nullptr,
                bias, M, K, Npix, 1, Cin, CPWlog, Wpad, Wolog, stride, astride);
        }
    };
    // fused offset-conv + deform (halo'ed NHWC f16 out)
    auto gemm_def = [&](const u16* A, const u16* actb, u16* outd,
                        int M, int K, int Npix, int Cin, int CPWlog,
                        int Wpad, int Wlog, size_t astride) {
        if (M == 64) {
            dim3 g(Npix / 256, 1, N);
            gemm_impl_k<1, 4, 1><<<g, TPB, 0, stream>>>(A, actb, nullptr, outd,
                nullptr, M, K, Npix, 0, Cin, CPWlog, Wpad, Wlog, 1, astride);
        } else {
            dim3 g(Npix / 128, M / 128, N);
            gemm_impl_k<2, 2, 1><<<g, TPB, 0, stream>>>(A, actb, nullptr, outd,
                nullptr, M, K, Npix, 0, Cin, CPWlog, Wpad, Wlog, 1, astride);
        }
    };
    auto bn_t = [&](const float* src, const float* g_, const float* b_,
                    u16* dst, int C, int HWlog, int Wlog, int Wpad,
                    size_t ostride) {
        int HW = 1 << HWlog, NHW = N * HW;
        zero_k<<<1, TPB, 0, stream>>>(STATS, 256);
        dim3 gs(32, C);
        bn_stats_k<<<gs, TPB, 0, stream>>>(src, STATS, C, HWlog, NHW, 32);
        dim3 ga(HW / 64, C / 32, N);
        bn_apply_t_k<<<ga, TPB, 0, stream>>>(src, STATS, g_, b_, dst, C, HWlog,
                                             Wlog, Wpad, ostride,
                                             1.f / (float)NHW);
    };

    const size_t AS1 = 540800;   // 130*130*32
    const size_t AS2 = 278784;   // 66*66*64
    const size_t AS3 = 557568;   // 66*66*128

    // ---- conv11 (1->32, 128x128, s1, direct) + relu -> fp32 NCHW ----
    {
        dim3 g(8, 8, N * 8);
        conv3x3_k<1><<<g, TPB, 0, stream>>>(x, c11w, c11b, SCRATCH, N, 1, 128,
                                            128, 32, 128, 128, 1, 0);
    }
    bn_t(SCRATCH, bn11g, bn11b, ACTB0, 32, 14, 7, 130, AS1);

    // ---- fused off12 + deform12: ACTB0 -> ACTB1 (AS1) ----
    gemm_def(wo12, ACTB0, ACTB1, 64, 288, 16384, 32, 0, 130, 7, AS1);
    // ---- conv12 (32->64, s2) ----
    gemm(wc12, ACTB1, SCRATCH, c12b, 64, 288, 4096, 32, 0, 130, 6, 2, AS1);
    zero_region(ACTB0, AS2 * N);
    bn_t(SCRATCH, bn12g, bn12b, ACTB0, 64, 12, 6, 66, AS2);

    // ---- fused off21 + deform21: ACTB0 -> ACTB1 (AS2) ----
    zero_region(ACTB1, AS2 * N);
    gemm_def(wo21, ACTB0, ACTB1, 128, 576, 4096, 64, 1, 66, 6, AS2);
    // ---- conv21 (64->128, s1) ----
    gemm(wc21, ACTB1, SCRATCH, c21b, 128, 576, 4096, 64, 1, 66, 6, 1, AS2);
    zero_region(ACTB0, AS3 * N);
    bn_t(SCRATCH, bn21g, bn21b, ACTB0, 128, 12, 6, 66, AS3);

    // ---- fused off22 + deform22: ACTB0 -> ACTB1 (AS3) ----
    zero_region(ACTB1, AS3 * N);
    gemm_def(wo22, ACTB0, ACTB1, 256, 1152, 4096, 128, 2, 66, 6, AS3);
    // ---- conv22 (128->128, s2) ----
    gemm(wc22, ACTB1, SCRATCH, c22b, 128, 1152, 1024, 128, 2, 66, 5, 2, AS3);
    {   // bn22 in place (fp32 NCHW), GAP follows
        int HW = 1024, NHW = N * HW, total = N * 128 * HW;
        zero_k<<<1, TPB, 0, stream>>>(STATS, 256);
        dim3 gs(32, 128);
        bn_stats_k<<<gs, TPB, 0, stream>>>(SCRATCH, STATS, 128, 10, NHW, 32);
        bn_apply_k<<<(total + TPB - 1) / TPB, TPB, 0, stream>>>(
            SCRATCH, STATS, bn22g, bn22b, 127, 10, 1.f / (float)NHW, total);
    }

    // ---- GAP + FC + softmax ----
    gap_k<<<N * 128, 64, 0, stream>>>(SCRATCH, POOLED, 1024, 1.f / 1024.f);
    fc_softmax_k<<<N, 64, 0, stream>>>(POOLED, fcw, fcb, outp);
}

// Round 8
// 744.543 us; speedup vs baseline: 1.0990x; 1.0990x over previous
//
#include <hip/hip_runtime.h>
#include <math.h>

#define TPB 256
typedef unsigned short u16;
typedef _Float16 v8h __attribute__((ext_vector_type(8)));
typedef float v4f __attribute__((ext_vector_type(4)));

__device__ __forceinline__ u16 f2h(float v) {
    return __builtin_bit_cast(u16, (_Float16)v);
}
__device__ __forceinline__ float h2f(u16 v) {
    return (float)__builtin_bit_cast(_Float16, v);
}

typedef const __attribute__((address_space(1))) unsigned int* gp1_t;
typedef __attribute__((address_space(3))) unsigned int* lp3_t;
__device__ __forceinline__ void gload_lds16(const void* g, void* l) {
    __builtin_amdgcn_global_load_lds((gp1_t)g, (lp3_t)l, 16, 0, 0);
}

// ---------------------------------------------------------------------------
// weight cast + permute: OIHW fp32 -> [co][ky*3+kx][ci] f16
// ---------------------------------------------------------------------------
__global__ __launch_bounds__(256) void cast_perm_k(
    const float* __restrict__ src, u16* __restrict__ dst, int Cout, int Cin)
{
    int i = blockIdx.x * TPB + threadIdx.x;
    int total = Cout * Cin * 9;
    if (i >= total) return;
    int ci = i % Cin, rest = i / Cin;
    int w = rest % 9, co = rest / 9;
    dst[i] = f2h(src[(co * Cin + ci) * 9 + w]);
}

__global__ __launch_bounds__(256) void zero4_k(uint4* __restrict__ p, int n)
{
    int i = blockIdx.x * TPB + threadIdx.x;
    if (i < n) p[i] = (uint4){0u, 0u, 0u, 0u};
}

// ---------------------------------------------------------------------------
// Implicit-GEMM conv from HALO'ed NHWC f16 act ((H+2)x(W+2)xC per image,
// interior pixel (y,x) at ((y+1)*Wpad+(x+1))*C, halo cells zero -> no bounds
// predication -> every B row-chunk is an unconditional 16B global_load_lds.
// Double-buffered LDS; loads for step k+1 issued right after the barrier,
// drained by the next iteration's vmcnt(0) -> fetch overlaps MFMA.
// XOR swizzle c ^ ((row>>1)&3): DMA stays lane-contiguous, ds_read_b128
// 2-way aliased only (free). Block = 4 waves, wave tile 64x64 (4x4 mfma
// 16x16x32 f16); block tile (WGM*64)x(WGN*64).
// F16OUT=0: fp32 NCHW C (+bias,relu).  F16OUT=1: f16 NCHW C (offset conv).
// ---------------------------------------------------------------------------
template <int WGM, int WGN, int F16OUT>
__global__ __launch_bounds__(256) void gemm_impl_k(
    const u16* __restrict__ A, const u16* __restrict__ act, float* __restrict__ C,
    u16* __restrict__ C16, const float* __restrict__ bias,
    int M, int K, int Npix, int relu,
    int Cin, int CPWlog, int Wpad, int Wolog, int stride, size_t astride)
{
    constexpr int BM = WGM * 64, BN = WGN * 64;
    constexpr int ASLOTS = BM / 16, BSLOTS = BN / 16;
    constexpr int SLOTS = ASLOTS + BSLOTS, SPW = SLOTS / 4;
    __shared__ u16 lds[2][(BM + BN) * 32];
    const int t = threadIdx.x, lane = t & 63, wave = t >> 6;
    const int g = blockIdx.z;
    const int p0 = blockIdx.x * BN, m0 = blockIdx.y * BM;
    const u16* actg = act + (size_t)g * astride;
    const int Wo = 1 << Wolog;

    const u16* src[SPW];
#pragma unroll
    for (int i = 0; i < SPW; ++i) {
        int s = wave * SPW + i;
        if (s < ASLOTS) {
            int ch = s * 64 + lane, nr = ch >> 2, cst = ch & 3;
            int csrc = cst ^ ((nr >> 1) & 3);
            src[i] = A + (size_t)(m0 + nr) * K + csrc * 8;
        } else {
            int ch = (s - ASLOTS) * 64 + lane, nr = ch >> 2, cst = ch & 3;
            int csrc = cst ^ ((nr >> 1) & 3);
            int p = p0 + nr, oy = p >> Wolog, ox = p & (Wo - 1);
            src[i] = actg + (size_t)(oy * stride * Wpad + ox * stride) * Cin + csrc * 8;
        }
    }

    auto issue = [&](int kk, int buf) {
        int k0 = kk << 5;
        int w = kk >> CPWlog;
        int ci0 = (kk & ((1 << CPWlog) - 1)) << 5;
        int koff = (w / 3 * Wpad + w % 3) * Cin + ci0;
#pragma unroll
        for (int i = 0; i < SPW; ++i) {
            int s = wave * SPW + i;
            const u16* sp = src[i] + ((s < ASLOTS) ? k0 : koff);
            gload_lds16(sp, lds[buf] + s * 512);
        }
    };

    v4f acc[4][4];
#pragma unroll
    for (int mi = 0; mi < 4; ++mi)
#pragma unroll
        for (int ni = 0; ni < 4; ++ni) acc[mi][ni] = (v4f){0.f, 0.f, 0.f, 0.f};

    const int wm = wave % WGM, wn = wave / WGM;
    const int la = lane & 15, quad = lane >> 4;

    issue(0, 0);
    const int nk = K >> 5;
    for (int kk = 0; kk < nk; ++kk) {
        int buf = kk & 1;
        asm volatile("s_waitcnt vmcnt(0)\n\ts_barrier" ::: "memory");
        if (kk + 1 < nk) issue(kk + 1, buf ^ 1);
        const u16* Lb = lds[buf];
        v8h a[4], b[4];
#pragma unroll
        for (int mi = 0; mi < 4; ++mi) {
            int r = wm * 64 + mi * 16 + la;
            a[mi] = *(const v8h*)(Lb + (r * 4 + (quad ^ ((r >> 1) & 3))) * 8);
        }
#pragma unroll
        for (int ni = 0; ni < 4; ++ni) {
            int r = wn * 64 + ni * 16 + la;
            b[ni] = *(const v8h*)(Lb + BM * 32 + (r * 4 + (quad ^ ((r >> 1) & 3))) * 8);
        }
#pragma unroll
        for (int mi = 0; mi < 4; ++mi)
#pragma unroll
            for (int ni = 0; ni < 4; ++ni)
                acc[mi][ni] = __builtin_amdgcn_mfma_f32_16x16x32_f16(
                    a[mi], b[ni], acc[mi][ni], 0, 0, 0);
    }

    if (!F16OUT) {
        float* Cimg = C + (size_t)g * M * Npix;
#pragma unroll
        for (int mi = 0; mi < 4; ++mi) {
#pragma unroll
            for (int r = 0; r < 4; ++r) {
                int row = m0 + wm * 64 + mi * 16 + quad * 4 + r;
                float bv = bias ? bias[row] : 0.f;
#pragma unroll
                for (int ni = 0; ni < 4; ++ni) {
                    int col = p0 + wn * 64 + ni * 16 + la;
                    float v = acc[mi][ni][r] + bv;
                    if (relu) v = fmaxf(v, 0.f);
                    Cimg[(size_t)row * Npix + col] = v;
                }
            }
        }
    } else {
        u16* og = C16 + (size_t)g * M * Npix;
#pragma unroll
        for (int mi = 0; mi < 4; ++mi) {
#pragma unroll
            for (int r = 0; r < 4; ++r) {
                int row = m0 + wm * 64 + mi * 16 + quad * 4 + r;
#pragma unroll
                for (int ni = 0; ni < 4; ++ni) {
                    int col = p0 + wn * 64 + ni * 16 + la;
                    og[(size_t)row * Npix + col] = f2h(acc[mi][ni][r]);
                }
            }
        }
    }
}

// ---------------------------------------------------------------------------
// Direct 3x3 conv (conv11 only, Cin=1), fp32 NCHW out
// ---------------------------------------------------------------------------
template <int STRIDE>
__global__ __launch_bounds__(256) void conv3x3_k(
    const float* __restrict__ in, const float* __restrict__ wgt,
    const float* __restrict__ bias, float* __restrict__ out,
    int N, int Cin, int H, int W, int Cout_buf, int Ho, int Wo,
    int relu, int co_base)
{
    constexpr int IT = 15 * STRIDE + 3;
    __shared__ float tile[IT * IT];
    const int tid = threadIdx.x;
    const int tx = tid & 15, ty = tid >> 4;
    const int coutg = Cout_buf >> 2;
    const int n = blockIdx.z / coutg;
    const int cog = blockIdx.z - n * coutg;
    const int co0 = cog << 2;
    const int ox = (blockIdx.x << 4) + tx;
    const int oy = (blockIdx.y << 4) + ty;
    const int ix0 = (blockIdx.x << 4) * STRIDE - 1;
    const int iy0 = (blockIdx.y << 4) * STRIDE - 1;
    const float* inN = in + (size_t)n * Cin * H * W;
    float acc[4] = {0.f, 0.f, 0.f, 0.f};

    for (int ci = 0; ci < Cin; ++ci) {
        const float* plane = inN + (size_t)ci * H * W;
        __syncthreads();
        for (int i = tid; i < IT * IT; i += TPB) {
            int r = i / IT, c = i - r * IT;
            int yy = iy0 + r, xx = ix0 + c;
            float v = 0.f;
            if (yy >= 0 && yy < H && xx >= 0 && xx < W) v = plane[yy * W + xx];
            tile[i] = v;
        }
        __syncthreads();
        const int ly = ty * STRIDE, lx = tx * STRIDE;
        float nb[9];
#pragma unroll
        for (int ky = 0; ky < 3; ++ky)
#pragma unroll
            for (int kx = 0; kx < 3; ++kx)
                nb[ky * 3 + kx] = tile[(ly + ky) * IT + lx + kx];
        const float* wp = wgt + ((size_t)(co_base + co0) * Cin + ci) * 9;
#pragma unroll
        for (int j = 0; j < 4; ++j) {
            const float* w9 = wp + (size_t)j * Cin * 9;
            float a = acc[j];
#pragma unroll
            for (int k = 0; k < 9; ++k) a += nb[k] * w9[k];
            acc[j] = a;
        }
    }
#pragma unroll
    for (int j = 0; j < 4; ++j) {
        float v = acc[j];
        if (bias) v += bias[co_base + co0 + j];
        if (relu) v = fmaxf(v, 0.f);
        out[(((size_t)n * Cout_buf + (co0 + j)) * Ho + oy) * Wo + ox] = v;
    }
}

// ---------------------------------------------------------------------------
// BatchNorm
// ---------------------------------------------------------------------------
__global__ void zero_k(float* p, int n)
{
    int i = blockIdx.x * TPB + threadIdx.x;
    if (i < n) p[i] = 0.f;
}

__global__ __launch_bounds__(256) void bn_stats_k(
    const float* __restrict__ x, float* __restrict__ stats,
    int C, int HWlog, int NHW, int SPLIT)
{
    const int c = blockIdx.y, sb = blockIdx.x, tid = threadIdx.x;
    const int HWm = (1 << HWlog) - 1;
    float s = 0.f, s2 = 0.f;
    for (int i = sb * TPB + tid; i < NHW; i += SPLIT * TPB) {
        int nn = i >> HWlog, p = i & HWm;
        float v = x[(((size_t)nn * C + c) << HWlog) + p];
        s += v;
        s2 += v * v;
    }
    __shared__ float r1[TPB], r2[TPB];
    r1[tid] = s; r2[tid] = s2;
    __syncthreads();
    for (int d = TPB / 2; d > 0; d >>= 1) {
        if (tid < d) { r1[tid] += r1[tid + d]; r2[tid] += r2[tid + d]; }
        __syncthreads();
    }
    if (tid == 0) {
        atomicAdd(&stats[2 * c], r1[0]);
        atomicAdd(&stats[2 * c + 1], r2[0]);
    }
}

// in-place fp32 NCHW apply (last BN only)
__global__ __launch_bounds__(256) void bn_apply_k(
    float* __restrict__ x, const float* __restrict__ stats,
    const float* __restrict__ g, const float* __restrict__ b,
    int Cm1, int HWlog, float invcnt, int total)
{
    int idx = blockIdx.x * TPB + threadIdx.x;
    if (idx >= total) return;
    int c = (idx >> HWlog) & Cm1;
    float mean = stats[2 * c] * invcnt;
    float var  = fmaxf(stats[2 * c + 1] * invcnt - mean * mean, 0.f);
    float sc   = g[c] / sqrtf(var + 1e-5f);
    x[idx] = (x[idx] - mean) * sc + b[c];
}

// fused BN-apply + NCHW->halo'ed-NHWC transpose + f16 cast.
// grid (HW/64, C/32, N)
__global__ __launch_bounds__(256) void bn_apply_t_k(
    const float* __restrict__ x, const float* __restrict__ stats,
    const float* __restrict__ gamma, const float* __restrict__ beta,
    u16* __restrict__ out, int C, int HWlog, int Wlog, int Wpad,
    size_t ostride, float invcnt)
{
    __shared__ float tile[32 * 65];
    __shared__ float smean[32], ssc[32], sb2[32];
    int t = threadIdx.x;
    int img = blockIdx.z, c0 = blockIdx.y * 32, p0 = blockIdx.x * 64;
    if (t < 32) {
        int c = c0 + t;
        float mean = stats[2 * c] * invcnt;
        float var = fmaxf(stats[2 * c + 1] * invcnt - mean * mean, 0.f);
        smean[t] = mean;
        ssc[t] = gamma[c] / sqrtf(var + 1e-5f);
        sb2[t] = beta[c];
    }
    __syncthreads();
    const float* xi = x + (((size_t)img * C) << HWlog);
    u16* oi = out + (size_t)img * ostride;
    const int Wm1 = (1 << Wlog) - 1;
#pragma unroll
    for (int i = 0; i < 8; ++i) {
        int e = t + i * 256;
        int cl = e >> 6, pp = e & 63;
        float v = xi[(((size_t)(c0 + cl)) << HWlog) + p0 + pp];
        tile[cl * 65 + pp] = (v - smean[cl]) * ssc[cl] + sb2[cl];
    }
    __syncthreads();
#pragma unroll
    for (int i = 0; i < 8; ++i) {
        int e = t + i * 256;
        int cl = e & 31, pp = e >> 5;
        int p = p0 + pp, y = p >> Wlog, xx = p & Wm1;
        oi[((size_t)(y + 1) * Wpad + (xx + 1)) * C + c0 + cl] =
            f2h(tile[cl * 65 + pp]);
    }
}

// ---------------------------------------------------------------------------
// Deform on halo'ed NHWC f16. off is f16 [img][2C][HW] (offset GEMM output);
// for flat (c,p): (dy,dx) = 2 halves at off_img + 2*(c*HW+p) — the
// torch-faithful (b,2c,h,w)->(b*c,h*w,2) flat semantics. Phase 1 stages
// offsets p-major (coalesced 4B) into LDS; phase 2 c-major: gathers
// channel-contiguous act (coalesced 64B runs), writes halo'ed NHWC f16.
// grid (HW/64, C/32, N)
// ---------------------------------------------------------------------------
__global__ __launch_bounds__(256) void deform_nhwc_k(
    const u16* __restrict__ actb, const u16* __restrict__ off,
    u16* __restrict__ out, int C, int HWlog, int Wlog, int H, int W,
    int Wpad, size_t astride)
{
    __shared__ float DY[32 * 65], DX[32 * 65];
    int t = threadIdx.x;
    int img = blockIdx.z, c0 = blockIdx.y * 32, p0 = blockIdx.x * 64;
    const u16* offg = off + (size_t)img * (((size_t)2 * C) << HWlog);
#pragma unroll
    for (int i = 0; i < 8; ++i) {
        int e = t + i * 256;
        int cl = e >> 6, pp = e & 63;
        size_t idx_pc = (((size_t)(c0 + cl)) << HWlog) + p0 + pp;
        unsigned int ov = *(const unsigned int*)(offg + 2 * idx_pc);
        DY[cl * 65 + pp] = h2f((u16)(ov & 0xffffu));
        DX[cl * 65 + pp] = h2f((u16)(ov >> 16));
    }
    __syncthreads();
    const u16* ai = actb + (size_t)img * astride;
    u16* oi = out + (size_t)img * astride;
#pragma unroll
    for (int i = 0; i < 8; ++i) {
        int e = t + i * 256;
        int cl = e & 31, pp = e >> 5;
        int c = c0 + cl, p = p0 + pp;
        int yy = p >> Wlog, xx = p & (W - 1);
        float cy = fminf(fmaxf((float)yy + DY[cl * 65 + pp], 0.f), (float)(H - 1));
        float cx = fminf(fmaxf((float)xx + DX[cl * 65 + pp], 0.f), (float)(W - 1));
        float y0f = floorf(cy), x0f = floorf(cx);
        float ty = cy - y0f, tx = cx - x0f;
        int y0 = (int)y0f, y1 = (int)ceilf(cy);
        int x0 = (int)x0f, x1 = (int)ceilf(cx);
        float vlt = h2f(ai[((size_t)(y0 + 1) * Wpad + (x0 + 1)) * C + c]);
        float vrt = h2f(ai[((size_t)(y1 + 1) * Wpad + (x0 + 1)) * C + c]);
        float vlb = h2f(ai[((size_t)(y0 + 1) * Wpad + (x1 + 1)) * C + c]);
        float vrb = h2f(ai[((size_t)(y1 + 1) * Wpad + (x1 + 1)) * C + c]);
        float vt = ty * (vrt - vlt) + vlt;
        float vb = ty * (vrb - vlb) + vlb;
        oi[((size_t)(yy + 1) * Wpad + (xx + 1)) * C + c] = f2h(tx * (vb - vt) + vt);
    }
}

// ---------------------------------------------------------------------------
__global__ __launch_bounds__(64) void gap_k(
    const float* __restrict__ x, float* __restrict__ pooled, int HW, float inv)
{
    int bc = blockIdx.x;
    float s = 0.f;
    for (int i = threadIdx.x; i < HW; i += 64) s += x[(size_t)bc * HW + i];
#pragma unroll
    for (int d = 32; d > 0; d >>= 1) s += __shfl_down(s, d);
    if (threadIdx.x == 0) pooled[bc] = s * inv;
}

__global__ __launch_bounds__(64) void fc_softmax_k(
    const float* __restrict__ pooled, const float* __restrict__ fw,
    const float* __restrict__ fb, float* __restrict__ outp)
{
    int n = blockIdx.x;
    __shared__ float logits[10];
    int k = threadIdx.x;
    if (k < 10) {
        float s = fb[k];
        const float* row = pooled + n * 128;
        const float* wr  = fw + k * 128;
        for (int c = 0; c < 128; ++c) s += row[c] * wr[c];
        logits[k] = s;
    }
    __syncthreads();
    if (k < 10) {
        float m = logits[0];
#pragma unroll
        for (int j = 1; j < 10; ++j) m = fmaxf(m, logits[j]);
        float den = 0.f;
#pragma unroll
        for (int j = 0; j < 10; ++j) den += expf(logits[j] - m);
        outp[n * 10 + k] = expf(logits[k] - m) / den;
    }
}

// ---------------------------------------------------------------------------
// Workspace (~143.9 MB, proven safe):
//   SCRATCH 16,777,216 f (64 MiB) -- fp32 conv outputs OR f16 offset tensors
//     (disjoint lifetimes). f16 OFF: st1 = 64*16384*32 u16 = 64 MiB exactly,
//     st2 = 32 MiB, st3 = 256*4096*32 u16 = 64 MiB exactly -> no chunking.
//   ACTB0   18,874,368 u16 (36 MB, halo'ed NHWC f16)
//   ACTB1   18,874,368 u16 (36 MB)
//   WBF + STATS/POOLED
// Halo'ed strides: AS1=130*130*32, AS2=66*66*64, AS3=66*66*128. Buffers are
// re-zeroed for each stage layout before reuse so halo cells stay 0.
// ---------------------------------------------------------------------------
extern "C" void kernel_launch(void* const* d_in, const int* in_sizes, int n_in,
                              void* d_out, int out_size, void* d_ws, size_t ws_size,
                              hipStream_t stream)
{
    const float* x     = (const float*)d_in[0];
    const float* c11w  = (const float*)d_in[1];
    const float* c11b  = (const float*)d_in[2];
    const float* bn11g = (const float*)d_in[3];
    const float* bn11b = (const float*)d_in[4];
    const float* o12w  = (const float*)d_in[5];
    const float* c12w  = (const float*)d_in[6];
    const float* c12b  = (const float*)d_in[7];
    const float* bn12g = (const float*)d_in[8];
    const float* bn12b = (const float*)d_in[9];
    const float* o21w  = (const float*)d_in[10];
    const float* c21w  = (const float*)d_in[11];
    const float* c21b  = (const float*)d_in[12];
    const float* bn21g = (const float*)d_in[13];
    const float* bn21b = (const float*)d_in[14];
    const float* o22w  = (const float*)d_in[15];
    const float* c22w  = (const float*)d_in[16];
    const float* c22b  = (const float*)d_in[17];
    const float* bn22g = (const float*)d_in[18];
    const float* bn22b = (const float*)d_in[19];
    const float* fcw   = (const float*)d_in[20];
    const float* fcb   = (const float*)d_in[21];
    float* outp = (float*)d_out;

    const int N = 32;
    float* ws      = (float*)d_ws;
    float* SCRATCH = ws;                          // 16,777,216 floats (64 MiB)
    u16*   OFF     = (u16*)ws;                    // aliases SCRATCH (f16 offsets)
    u16*   ACTB0   = (u16*)(ws + 16777216);       // 18,874,368 u16 (36 MB)
    u16*   ACTB1   = (u16*)(ws + 26214400);       // 18,874,368 u16 (36 MB)
    u16*   WBF     = (u16*)(ws + 35651584);       // 626,688 u16
    float* STATS   = ws + 35964928;               // 256
    float* POOLED  = STATS + 256;                 // 4096

    auto zero_region = [&](u16* p, size_t n_u16) {
        int n4 = (int)(n_u16 / 8);
        zero4_k<<<(n4 + TPB - 1) / TPB, TPB, 0, stream>>>((uint4*)p, n4);
    };
    // initial zero of both act buffers (stage-1 AS1 halos); contiguous
    zero_region(ACTB0, 2u * 18874368u);

    u16* wo12 = WBF + 0;
    u16* wc12 = WBF + 18432;
    u16* wo21 = WBF + 36864;
    u16* wc21 = WBF + 110592;
    u16* wo22 = WBF + 184320;
    u16* wc22 = WBF + 479232;
    auto cast = [&](const float* s, u16* d, int Cout, int Cin) {
        int n = Cout * Cin * 9;
        cast_perm_k<<<(n + TPB - 1) / TPB, TPB, 0, stream>>>(s, d, Cout, Cin);
    };
    cast(o12w, wo12, 64, 32);
    cast(c12w, wc12, 64, 32);
    cast(o21w, wo21, 128, 64);
    cast(c21w, wc21, 128, 64);
    cast(o22w, wo22, 256, 128);
    cast(c22w, wc22, 128, 128);

    // conv GEMM -> fp32 NCHW (bias+relu)
    auto gemm = [&](const u16* A, const u16* actb, float* Cp, const float* bias,
                    int M, int K, int Npix, int Cin, int CPWlog,
                    int Wpad, int Wolog, int stride, size_t astride) {
        if (M == 64) {
            dim3 g(Npix / 256, 1, N);
            gemm_impl_k<1, 4, 0><<<g, TPB, 0, stream>>>(A, actb, Cp, nullptr,
                bias, M, K, Npix, 1, Cin, CPWlog, Wpad, Wolog, stride, astride);
        } else {
            dim3 g(Npix / 128, M / 128, N);
            gemm_impl_k<2, 2, 0><<<g, TPB, 0, stream>>>(A, actb, Cp, nullptr,
                bias, M, K, Npix, 1, Cin, CPWlog, Wpad, Wolog, stride, astride);
        }
    };
    // offset GEMM -> f16 NCHW (no bias/relu)
    auto gemm_off = [&](const u16* A, const u16* actb, u16* Cp,
                        int M, int K, int Npix, int Cin, int CPWlog,
                        int Wpad, int Wlog, size_t astride) {
        if (M == 64) {
            dim3 g(Npix / 256, 1, N);
            gemm_impl_k<1, 4, 1><<<g, TPB, 0, stream>>>(A, actb, nullptr, Cp,
                nullptr, M, K, Npix, 0, Cin, CPWlog, Wpad, Wlog, 1, astride);
        } else {
            dim3 g(Npix / 128, M / 128, N);
            gemm_impl_k<2, 2, 1><<<g, TPB, 0, stream>>>(A, actb, nullptr, Cp,
                nullptr, M, K, Npix, 0, Cin, CPWlog, Wpad, Wlog, 1, astride);
        }
    };
    auto bn_t = [&](const float* src, const float* g_, const float* b_,
                    u16* dst, int C, int HWlog, int Wlog, int Wpad,
                    size_t ostride) {
        int HW = 1 << HWlog, NHW = N * HW;
        zero_k<<<1, TPB, 0, stream>>>(STATS, 256);
        dim3 gs(32, C);
        bn_stats_k<<<gs, TPB, 0, stream>>>(src, STATS, C, HWlog, NHW, 32);
        dim3 ga(HW / 64, C / 32, N);
        bn_apply_t_k<<<ga, TPB, 0, stream>>>(src, STATS, g_, b_, dst, C, HWlog,
                                             Wlog, Wpad, ostride,
                                             1.f / (float)NHW);
    };
    // offset conv (full batch) + channel-coalesced bilinear deform
    auto deform_stage = [&](const u16* woff, int C, int HWlog, int Wlog,
                            int H, int W, int Wpad, size_t astride,
                            int K, int CPWlog) {
        int HW = 1 << HWlog;
        gemm_off(woff, ACTB0, OFF, 2 * C, K, HW, C, CPWlog, Wpad, Wlog, astride);
        dim3 g(HW / 64, C / 32, N);
        deform_nhwc_k<<<g, TPB, 0, stream>>>(ACTB0, OFF, ACTB1, C, HWlog, Wlog,
                                             H, W, Wpad, astride);
    };

    const size_t AS1 = 540800;   // 130*130*32
    const size_t AS2 = 278784;   // 66*66*64
    const size_t AS3 = 557568;   // 66*66*128

    // ---- conv11 (1->32, 128x128, s1, direct) + relu -> fp32 NCHW ----
    {
        dim3 g(8, 8, N * 8);
        conv3x3_k<1><<<g, TPB, 0, stream>>>(x, c11w, c11b, SCRATCH, N, 1, 128,
                                            128, 32, 128, 128, 1, 0);
    }
    bn_t(SCRATCH, bn11g, bn11b, ACTB0, 32, 14, 7, 130, AS1);

    // ---- off12 + deform12: ACTB0 -> ACTB1 (AS1), OFF = 64 MiB exactly ----
    deform_stage(wo12, 32, 14, 7, 128, 128, 130, AS1, 288, 0);
    // ---- conv12 (32->64, s2) ----
    gemm(wc12, ACTB1, SCRATCH, c12b, 64, 288, 4096, 32, 0, 130, 6, 2, AS1);
    zero_region(ACTB0, AS2 * N);
    bn_t(SCRATCH, bn12g, bn12b, ACTB0, 64, 12, 6, 66, AS2);

    // ---- off21 + deform21: ACTB0 -> ACTB1 (AS2), OFF = 32 MiB ----
    zero_region(ACTB1, AS2 * N);
    deform_stage(wo21, 64, 12, 6, 64, 64, 66, AS2, 576, 1);
    // ---- conv21 (64->128, s1) ----
    gemm(wc21, ACTB1, SCRATCH, c21b, 128, 576, 4096, 64, 1, 66, 6, 1, AS2);
    zero_region(ACTB0, AS3 * N);
    bn_t(SCRATCH, bn21g, bn21b, ACTB0, 128, 12, 6, 66, AS3);

    // ---- off22 + deform22: ACTB0 -> ACTB1 (AS3), OFF = 64 MiB exactly ----
    zero_region(ACTB1, AS3 * N);
    deform_stage(wo22, 128, 12, 6, 64, 64, 66, AS3, 1152, 2);
    // ---- conv22 (128->128, s2) ----
    gemm(wc22, ACTB1, SCRATCH, c22b, 128, 1152, 1024, 128, 2, 66, 5, 2, AS3);
    {   // bn22 in place (fp32 NCHW), GAP follows
        int HW = 1024, NHW = N * HW, total = N * 128 * HW;
        zero_k<<<1, TPB, 0, stream>>>(STATS, 256);
        dim3 gs(32, 128);
        bn_stats_k<<<gs, TPB, 0, stream>>>(SCRATCH, STATS, 128, 10, NHW, 32);
        bn_apply_k<<<(total + TPB - 1) / TPB, TPB, 0, stream>>>(
            SCRATCH, STATS, bn22g, bn22b, 127, 10, 1.f / (float)NHW, total);
    }

    // ---- GAP + FC + softmax ----
    gap_k<<<N * 128, 64, 0, stream>>>(SCRATCH, POOLED, 1024, 1.f / 1024.f);
    fc_softmax_k<<<N, 64, 0, stream>>>(POOLED, fcw, fcb, outp);
}

// Round 9
// 699.589 us; speedup vs baseline: 1.1696x; 1.0643x over previous
//
#include <hip/hip_runtime.h>
#include <math.h>

#define TPB 256
typedef unsigned short u16;
typedef _Float16 v8h __attribute__((ext_vector_type(8)));
typedef float v4f __attribute__((ext_vector_type(4)));

__device__ __forceinline__ u16 f2h(float v) {
    return __builtin_bit_cast(u16, (_Float16)v);
}
__device__ __forceinline__ float h2f(u16 v) {
    return (float)__builtin_bit_cast(_Float16, v);
}

typedef const __attribute__((address_space(1))) unsigned int* gp1_t;
typedef __attribute__((address_space(3))) unsigned int* lp3_t;
__device__ __forceinline__ void gload_lds16(const void* g, void* l) {
    __builtin_amdgcn_global_load_lds((gp1_t)g, (lp3_t)l, 16, 0, 0);
}

// ---------------------------------------------------------------------------
// weight cast + permute: OIHW fp32 -> [co][ky*3+kx][ci] f16
// ---------------------------------------------------------------------------
__global__ __launch_bounds__(256) void cast_perm_k(
    const float* __restrict__ src, u16* __restrict__ dst, int Cout, int Cin)
{
    int i = blockIdx.x * TPB + threadIdx.x;
    int total = Cout * Cin * 9;
    if (i >= total) return;
    int ci = i % Cin, rest = i / Cin;
    int w = rest % 9, co = rest / 9;
    dst[i] = f2h(src[(co * Cin + ci) * 9 + w]);
}

// zero only the 1-pixel halo ring of a padded NHWC image set.
// perimg = (2*Wpad + 2*(Hpad-2)) * C ; grid (ceil(perimg/256), N)
__global__ __launch_bounds__(256) void halo_zero_k(
    u16* __restrict__ buf, int Wpad, int Hpad, int C, int Clog,
    size_t astride, int perimg)
{
    int idx = blockIdx.x * TPB + threadIdx.x;
    int img = blockIdx.y;
    if (idx >= perimg) return;
    int hp = idx >> Clog, c = idx & (C - 1);
    int y, x;
    if (hp < Wpad) { y = 0; x = hp; }
    else if (hp < 2 * Wpad) { y = Hpad - 1; x = hp - Wpad; }
    else { int r = hp - 2 * Wpad; y = 1 + (r >> 1); x = (r & 1) ? (Wpad - 1) : 0; }
    buf[(size_t)img * astride + ((size_t)y * Wpad + x) * C + c] = 0;
}

// ---------------------------------------------------------------------------
// Implicit-GEMM conv from HALO'ed NHWC f16 act. Every B row-chunk is an
// unconditional 16B global_load_lds (zero halo -> no predication).
// K-loop: 3-stage / 3-LDS-buffer pipeline. Per wave: pre-issue k=0,1; each
// iter waits s_waitcnt vmcnt(SPW) (own k-loads drained, k+1 still in flight),
// barrier (=> buf k resident for ALL waves), issue k+2 into the buffer whose
// readers all passed this barrier, compute k. Loads get ~2 compute blocks to
// land (AITER-style fine-grained vmcnt, never 0 until the tail).
// XOR swizzle c ^ ((row>>1)&3): DMA lane-contiguous, ds_read_b128 2-way only.
// F16OUT=0: fp32 NCHW C (+bias,relu).  F16OUT=1: f16 NCHW C (offset conv).
// ---------------------------------------------------------------------------
template <int WGM, int WGN, int F16OUT>
__global__ __launch_bounds__(256) void gemm_impl_k(
    const u16* __restrict__ A, const u16* __restrict__ act, float* __restrict__ C,
    u16* __restrict__ C16, const float* __restrict__ bias,
    int M, int K, int Npix, int relu,
    int Cin, int CPWlog, int Wpad, int Wolog, int stride, size_t astride)
{
    constexpr int BM = WGM * 64, BN = WGN * 64;
    constexpr int ASLOTS = BM / 16, BSLOTS = BN / 16;
    constexpr int SLOTS = ASLOTS + BSLOTS, SPW = SLOTS / 4;
    __shared__ u16 lds[3][(BM + BN) * 32];
    const int t = threadIdx.x, lane = t & 63, wave = t >> 6;
    const int g = blockIdx.z;
    const int p0 = blockIdx.x * BN, m0 = blockIdx.y * BM;
    const u16* actg = act + (size_t)g * astride;
    const int Wo = 1 << Wolog;

    const u16* src[SPW];
#pragma unroll
    for (int i = 0; i < SPW; ++i) {
        int s = wave * SPW + i;
        if (s < ASLOTS) {
            int ch = s * 64 + lane, nr = ch >> 2, cst = ch & 3;
            int csrc = cst ^ ((nr >> 1) & 3);
            src[i] = A + (size_t)(m0 + nr) * K + csrc * 8;
        } else {
            int ch = (s - ASLOTS) * 64 + lane, nr = ch >> 2, cst = ch & 3;
            int csrc = cst ^ ((nr >> 1) & 3);
            int p = p0 + nr, oy = p >> Wolog, ox = p & (Wo - 1);
            src[i] = actg + (size_t)(oy * stride * Wpad + ox * stride) * Cin + csrc * 8;
        }
    }

    auto issue = [&](int kk, int buf) {
        int k0 = kk << 5;
        int w = kk >> CPWlog;
        int ci0 = (kk & ((1 << CPWlog) - 1)) << 5;
        int koff = (w / 3 * Wpad + w % 3) * Cin + ci0;
#pragma unroll
        for (int i = 0; i < SPW; ++i) {
            int s = wave * SPW + i;
            const u16* sp = src[i] + ((s < ASLOTS) ? k0 : koff);
            gload_lds16(sp, lds[buf] + s * 512);
        }
    };

    v4f acc[4][4];
#pragma unroll
    for (int mi = 0; mi < 4; ++mi)
#pragma unroll
        for (int ni = 0; ni < 4; ++ni) acc[mi][ni] = (v4f){0.f, 0.f, 0.f, 0.f};

    const int wm = wave % WGM, wn = wave / WGM;
    const int la = lane & 15, quad = lane >> 4;

    issue(0, 0);
    issue(1, 1);
    const int nk = K >> 5;      // always >= 9
    int rb = 0, wb = 2;
    for (int kk = 0; kk < nk; ++kk) {
        if (kk + 1 < nk) {
            // own k-loads drained; k+1 loads (SPW) stay in flight
            if constexpr (SPW == 4)
                asm volatile("s_waitcnt vmcnt(4)\n\ts_barrier" ::: "memory");
            else if constexpr (SPW == 5)
                asm volatile("s_waitcnt vmcnt(5)\n\ts_barrier" ::: "memory");
            else
                asm volatile("s_waitcnt vmcnt(0)\n\ts_barrier" ::: "memory");
            if (kk + 2 < nk) issue(kk + 2, wb);
        } else {
            asm volatile("s_waitcnt vmcnt(0)\n\ts_barrier" ::: "memory");
        }
        const u16* Lb = lds[rb];
        v8h a[4], b[4];
#pragma unroll
        for (int mi = 0; mi < 4; ++mi) {
            int r = wm * 64 + mi * 16 + la;
            a[mi] = *(const v8h*)(Lb + (r * 4 + (quad ^ ((r >> 1) & 3))) * 8);
        }
#pragma unroll
        for (int ni = 0; ni < 4; ++ni) {
            int r = wn * 64 + ni * 16 + la;
            b[ni] = *(const v8h*)(Lb + BM * 32 + (r * 4 + (quad ^ ((r >> 1) & 3))) * 8);
        }
#pragma unroll
        for (int mi = 0; mi < 4; ++mi)
#pragma unroll
            for (int ni = 0; ni < 4; ++ni)
                acc[mi][ni] = __builtin_amdgcn_mfma_f32_16x16x32_f16(
                    a[mi], b[ni], acc[mi][ni], 0, 0, 0);
        rb = (rb == 2) ? 0 : rb + 1;
        wb = (wb == 2) ? 0 : wb + 1;
    }

    if (!F16OUT) {
        float* Cimg = C + (size_t)g * M * Npix;
#pragma unroll
        for (int mi = 0; mi < 4; ++mi) {
#pragma unroll
            for (int r = 0; r < 4; ++r) {
                int row = m0 + wm * 64 + mi * 16 + quad * 4 + r;
                float bv = bias ? bias[row] : 0.f;
#pragma unroll
                for (int ni = 0; ni < 4; ++ni) {
                    int col = p0 + wn * 64 + ni * 16 + la;
                    float v = acc[mi][ni][r] + bv;
                    if (relu) v = fmaxf(v, 0.f);
                    Cimg[(size_t)row * Npix + col] = v;
                }
            }
        }
    } else {
        u16* og = C16 + (size_t)g * M * Npix;
#pragma unroll
        for (int mi = 0; mi < 4; ++mi) {
#pragma unroll
            for (int r = 0; r < 4; ++r) {
                int row = m0 + wm * 64 + mi * 16 + quad * 4 + r;
#pragma unroll
                for (int ni = 0; ni < 4; ++ni) {
                    int col = p0 + wn * 64 + ni * 16 + la;
                    og[(size_t)row * Npix + col] = f2h(acc[mi][ni][r]);
                }
            }
        }
    }
}

// ---------------------------------------------------------------------------
// Direct 3x3 conv (conv11 only, Cin=1), fp32 NCHW out
// ---------------------------------------------------------------------------
template <int STRIDE>
__global__ __launch_bounds__(256) void conv3x3_k(
    const float* __restrict__ in, const float* __restrict__ wgt,
    const float* __restrict__ bias, float* __restrict__ out,
    int N, int Cin, int H, int W, int Cout_buf, int Ho, int Wo,
    int relu, int co_base)
{
    constexpr int IT = 15 * STRIDE + 3;
    __shared__ float tile[IT * IT];
    const int tid = threadIdx.x;
    const int tx = tid & 15, ty = tid >> 4;
    const int coutg = Cout_buf >> 2;
    const int n = blockIdx.z / coutg;
    const int cog = blockIdx.z - n * coutg;
    const int co0 = cog << 2;
    const int ox = (blockIdx.x << 4) + tx;
    const int oy = (blockIdx.y << 4) + ty;
    const int ix0 = (blockIdx.x << 4) * STRIDE - 1;
    const int iy0 = (blockIdx.y << 4) * STRIDE - 1;
    const float* inN = in + (size_t)n * Cin * H * W;
    float acc[4] = {0.f, 0.f, 0.f, 0.f};

    for (int ci = 0; ci < Cin; ++ci) {
        const float* plane = inN + (size_t)ci * H * W;
        __syncthreads();
        for (int i = tid; i < IT * IT; i += TPB) {
            int r = i / IT, c = i - r * IT;
            int yy = iy0 + r, xx = ix0 + c;
            float v = 0.f;
            if (yy >= 0 && yy < H && xx >= 0 && xx < W) v = plane[yy * W + xx];
            tile[i] = v;
        }
        __syncthreads();
        const int ly = ty * STRIDE, lx = tx * STRIDE;
        float nb[9];
#pragma unroll
        for (int ky = 0; ky < 3; ++ky)
#pragma unroll
            for (int kx = 0; kx < 3; ++kx)
                nb[ky * 3 + kx] = tile[(ly + ky) * IT + lx + kx];
        const float* wp = wgt + ((size_t)(co_base + co0) * Cin + ci) * 9;
#pragma unroll
        for (int j = 0; j < 4; ++j) {
            const float* w9 = wp + (size_t)j * Cin * 9;
            float a = acc[j];
#pragma unroll
            for (int k = 0; k < 9; ++k) a += nb[k] * w9[k];
            acc[j] = a;
        }
    }
#pragma unroll
    for (int j = 0; j < 4; ++j) {
        float v = acc[j];
        if (bias) v += bias[co_base + co0 + j];
        if (relu) v = fmaxf(v, 0.f);
        out[(((size_t)n * Cout_buf + (co0 + j)) * Ho + oy) * Wo + ox] = v;
    }
}

// ---------------------------------------------------------------------------
// BatchNorm
// ---------------------------------------------------------------------------
__global__ void zero_k(float* p, int n)
{
    int i = blockIdx.x * TPB + threadIdx.x;
    if (i < n) p[i] = 0.f;
}

__global__ __launch_bounds__(256) void bn_stats_k(
    const float* __restrict__ x, float* __restrict__ stats,
    int C, int HWlog, int NHW, int SPLIT)
{
    const int c = blockIdx.y, sb = blockIdx.x, tid = threadIdx.x;
    const int HWm = (1 << HWlog) - 1;
    float s = 0.f, s2 = 0.f;
    for (int i = sb * TPB + tid; i < NHW; i += SPLIT * TPB) {
        int nn = i >> HWlog, p = i & HWm;
        float v = x[(((size_t)nn * C + c) << HWlog) + p];
        s += v;
        s2 += v * v;
    }
    __shared__ float r1[TPB], r2[TPB];
    r1[tid] = s; r2[tid] = s2;
    __syncthreads();
    for (int d = TPB / 2; d > 0; d >>= 1) {
        if (tid < d) { r1[tid] += r1[tid + d]; r2[tid] += r2[tid + d]; }
        __syncthreads();
    }
    if (tid == 0) {
        atomicAdd(&stats[2 * c], r1[0]);
        atomicAdd(&stats[2 * c + 1], r2[0]);
    }
}

// in-place fp32 NCHW apply (last BN only)
__global__ __launch_bounds__(256) void bn_apply_k(
    float* __restrict__ x, const float* __restrict__ stats,
    const float* __restrict__ g, const float* __restrict__ b,
    int Cm1, int HWlog, float invcnt, int total)
{
    int idx = blockIdx.x * TPB + threadIdx.x;
    if (idx >= total) return;
    int c = (idx >> HWlog) & Cm1;
    float mean = stats[2 * c] * invcnt;
    float var  = fmaxf(stats[2 * c + 1] * invcnt - mean * mean, 0.f);
    float sc   = g[c] / sqrtf(var + 1e-5f);
    x[idx] = (x[idx] - mean) * sc + b[c];
}

// fused BN-apply + NCHW->halo'ed-NHWC transpose + f16 cast.
// grid (HW/64, C/32, N)
__global__ __launch_bounds__(256) void bn_apply_t_k(
    const float* __restrict__ x, const float* __restrict__ stats,
    const float* __restrict__ gamma, const float* __restrict__ beta,
    u16* __restrict__ out, int C, int HWlog, int Wlog, int Wpad,
    size_t ostride, float invcnt)
{
    __shared__ float tile[32 * 65];
    __shared__ float smean[32], ssc[32], sb2[32];
    int t = threadIdx.x;
    int img = blockIdx.z, c0 = blockIdx.y * 32, p0 = blockIdx.x * 64;
    if (t < 32) {
        int c = c0 + t;
        float mean = stats[2 * c] * invcnt;
        float var = fmaxf(stats[2 * c + 1] * invcnt - mean * mean, 0.f);
        smean[t] = mean;
        ssc[t] = gamma[c] / sqrtf(var + 1e-5f);
        sb2[t] = beta[c];
    }
    __syncthreads();
    const float* xi = x + (((size_t)img * C) << HWlog);
    u16* oi = out + (size_t)img * ostride;
    const int Wm1 = (1 << Wlog) - 1;
#pragma unroll
    for (int i = 0; i < 8; ++i) {
        int e = t + i * 256;
        int cl = e >> 6, pp = e & 63;
        float v = xi[(((size_t)(c0 + cl)) << HWlog) + p0 + pp];
        tile[cl * 65 + pp] = (v - smean[cl]) * ssc[cl] + sb2[cl];
    }
    __syncthreads();
#pragma unroll
    for (int i = 0; i < 8; ++i) {
        int e = t + i * 256;
        int cl = e & 31, pp = e >> 5;
        int p = p0 + pp, y = p >> Wlog, xx = p & Wm1;
        oi[((size_t)(y + 1) * Wpad + (xx + 1)) * C + c0 + cl] =
            f2h(tile[cl * 65 + pp]);
    }
}

// ---------------------------------------------------------------------------
// Deform on halo'ed NHWC f16. off is f16 [img][2C][HW]; for flat (c,p):
// (dy,dx) = 2 halves at off_img + 2*(c*HW+p) (torch-faithful reshape).
// Phase 1 stages offsets p-major into LDS; phase 2 c-major: gathers
// channel-contiguous act, writes halo'ed NHWC f16.  grid (HW/64, C/32, N)
// ---------------------------------------------------------------------------
__global__ __launch_bounds__(256) void deform_nhwc_k(
    const u16* __restrict__ actb, const u16* __restrict__ off,
    u16* __restrict__ out, int C, int HWlog, int Wlog, int H, int W,
    int Wpad, size_t astride)
{
    __shared__ float DY[32 * 65], DX[32 * 65];
    int t = threadIdx.x;
    int img = blockIdx.z, c0 = blockIdx.y * 32, p0 = blockIdx.x * 64;
    const u16* offg = off + (size_t)img * (((size_t)2 * C) << HWlog);
#pragma unroll
    for (int i = 0; i < 8; ++i) {
        int e = t + i * 256;
        int cl = e >> 6, pp = e & 63;
        size_t idx_pc = (((size_t)(c0 + cl)) << HWlog) + p0 + pp;
        unsigned int ov = *(const unsigned int*)(offg + 2 * idx_pc);
        DY[cl * 65 + pp] = h2f((u16)(ov & 0xffffu));
        DX[cl * 65 + pp] = h2f((u16)(ov >> 16));
    }
    __syncthreads();
    const u16* ai = actb + (size_t)img * astride;
    u16* oi = out + (size_t)img * astride;
#pragma unroll
    for (int i = 0; i < 8; ++i) {
        int e = t + i * 256;
        int cl = e & 31, pp = e >> 5;
        int c = c0 + cl, p = p0 + pp;
        int yy = p >> Wlog, xx = p & (W - 1);
        float cy = fminf(fmaxf((float)yy + DY[cl * 65 + pp], 0.f), (float)(H - 1));
        float cx = fminf(fmaxf((float)xx + DX[cl * 65 + pp], 0.f), (float)(W - 1));
        float y0f = floorf(cy), x0f = floorf(cx);
        float ty = cy - y0f, tx = cx - x0f;
        int y0 = (int)y0f, y1 = (int)ceilf(cy);
        int x0 = (int)x0f, x1 = (int)ceilf(cx);
        float vlt = h2f(ai[((size_t)(y0 + 1) * Wpad + (x0 + 1)) * C + c]);
        float vrt = h2f(ai[((size_t)(y1 + 1) * Wpad + (x0 + 1)) * C + c]);
        float vlb = h2f(ai[((size_t)(y0 + 1) * Wpad + (x1 + 1)) * C + c]);
        float vrb = h2f(ai[((size_t)(y1 + 1) * Wpad + (x1 + 1)) * C + c]);
        float vt = ty * (vrt - vlt) + vlt;
        float vb = ty * (vrb - vlb) + vlb;
        oi[((size_t)(yy + 1) * Wpad + (xx + 1)) * C + c] = f2h(tx * (vb - vt) + vt);
    }
}

// ---------------------------------------------------------------------------
__global__ __launch_bounds__(64) void gap_k(
    const float* __restrict__ x, float* __restrict__ pooled, int HW, float inv)
{
    int bc = blockIdx.x;
    float s = 0.f;
    for (int i = threadIdx.x; i < HW; i += 64) s += x[(size_t)bc * HW + i];
#pragma unroll
    for (int d = 32; d > 0; d >>= 1) s += __shfl_down(s, d);
    if (threadIdx.x == 0) pooled[bc] = s * inv;
}

__global__ __launch_bounds__(64) void fc_softmax_k(
    const float* __restrict__ pooled, const float* __restrict__ fw,
    const float* __restrict__ fb, float* __restrict__ outp)
{
    int n = blockIdx.x;
    __shared__ float logits[10];
    int k = threadIdx.x;
    if (k < 10) {
        float s = fb[k];
        const float* row = pooled + n * 128;
        const float* wr  = fw + k * 128;
        for (int c = 0; c < 128; ++c) s += row[c] * wr[c];
        logits[k] = s;
    }
    __syncthreads();
    if (k < 10) {
        float m = logits[0];
#pragma unroll
        for (int j = 1; j < 10; ++j) m = fmaxf(m, logits[j]);
        float den = 0.f;
#pragma unroll
        for (int j = 0; j < 10; ++j) den += expf(logits[j] - m);
        outp[n * 10 + k] = expf(logits[k] - m) / den;
    }
}

// ---------------------------------------------------------------------------
// Workspace (~143.9 MB, proven safe). SCRATCH (64 MiB) holds fp32 conv
// outputs OR f16 offset tensors (disjoint lifetimes). ACTB0/ACTB1 are
// halo'ed NHWC f16; only the halo RING is zeroed per (buffer, layout) —
// interiors are fully overwritten by bn_apply_t / deform before any read.
// ---------------------------------------------------------------------------
extern "C" void kernel_launch(void* const* d_in, const int* in_sizes, int n_in,
                              void* d_out, int out_size, void* d_ws, size_t ws_size,
                              hipStream_t stream)
{
    const float* x     = (const float*)d_in[0];
    const float* c11w  = (const float*)d_in[1];
    const float* c11b  = (const float*)d_in[2];
    const float* bn11g = (const float*)d_in[3];
    const float* bn11b = (const float*)d_in[4];
    const float* o12w  = (const float*)d_in[5];
    const float* c12w  = (const float*)d_in[6];
    const float* c12b  = (const float*)d_in[7];
    const float* bn12g = (const float*)d_in[8];
    const float* bn12b = (const float*)d_in[9];
    const float* o21w  = (const float*)d_in[10];
    const float* c21w  = (const float*)d_in[11];
    const float* c21b  = (const float*)d_in[12];
    const float* bn21g = (const float*)d_in[13];
    const float* bn21b = (const float*)d_in[14];
    const float* o22w  = (const float*)d_in[15];
    const float* c22w  = (const float*)d_in[16];
    const float* c22b  = (const float*)d_in[17];
    const float* bn22g = (const float*)d_in[18];
    const float* bn22b = (const float*)d_in[19];
    const float* fcw   = (const float*)d_in[20];
    const float* fcb   = (const float*)d_in[21];
    float* outp = (float*)d_out;

    const int N = 32;
    float* ws      = (float*)d_ws;
    float* SCRATCH = ws;                          // 16,777,216 floats (64 MiB)
    u16*   OFF     = (u16*)ws;                    // aliases SCRATCH (f16 offsets)
    u16*   ACTB0   = (u16*)(ws + 16777216);       // 18,874,368 u16 (36 MB)
    u16*   ACTB1   = (u16*)(ws + 26214400);       // 18,874,368 u16 (36 MB)
    u16*   WBF     = (u16*)(ws + 35651584);       // 626,688 u16
    float* STATS   = ws + 35964928;               // 256
    float* POOLED  = STATS + 256;                 // 4096

    auto halo_zero = [&](u16* p, int Wpad, int Hpad, int C, int Clog,
                         size_t astride) {
        int perimg = (2 * Wpad + 2 * (Hpad - 2)) * C;
        dim3 g((perimg + TPB - 1) / TPB, N);
        halo_zero_k<<<g, TPB, 0, stream>>>(p, Wpad, Hpad, C, Clog, astride, perimg);
    };

    u16* wo12 = WBF + 0;
    u16* wc12 = WBF + 18432;
    u16* wo21 = WBF + 36864;
    u16* wc21 = WBF + 110592;
    u16* wo22 = WBF + 184320;
    u16* wc22 = WBF + 479232;
    auto cast = [&](const float* s, u16* d, int Cout, int Cin) {
        int n = Cout * Cin * 9;
        cast_perm_k<<<(n + TPB - 1) / TPB, TPB, 0, stream>>>(s, d, Cout, Cin);
    };
    cast(o12w, wo12, 64, 32);
    cast(c12w, wc12, 64, 32);
    cast(o21w, wo21, 128, 64);
    cast(c21w, wc21, 128, 64);
    cast(o22w, wo22, 256, 128);
    cast(c22w, wc22, 128, 128);

    // conv GEMM -> fp32 NCHW (bias+relu)
    auto gemm = [&](const u16* A, const u16* actb, float* Cp, const float* bias,
                    int M, int K, int Npix, int Cin, int CPWlog,
                    int Wpad, int Wolog, int stride, size_t astride) {
        if (M == 64) {
            dim3 g(Npix / 256, 1, N);
            gemm_impl_k<1, 4, 0><<<g, TPB, 0, stream>>>(A, actb, Cp, nullptr,
                bias, M, K, Npix, 1, Cin, CPWlog, Wpad, Wolog, stride, astride);
        } else {
            dim3 g(Npix / 128, M / 128, N);
            gemm_impl_k<2, 2, 0><<<g, TPB, 0, stream>>>(A, actb, Cp, nullptr,
                bias, M, K, Npix, 1, Cin, CPWlog, Wpad, Wolog, stride, astride);
        }
    };
    // offset GEMM -> f16 NCHW (no bias/relu)
    auto gemm_off = [&](const u16* A, const u16* actb, u16* Cp,
                        int M, int K, int Npix, int Cin, int CPWlog,
                        int Wpad, int Wlog, size_t astride) {
        if (M == 64) {
            dim3 g(Npix / 256, 1, N);
            gemm_impl_k<1, 4, 1><<<g, TPB, 0, stream>>>(A, actb, nullptr, Cp,
                nullptr, M, K, Npix, 0, Cin, CPWlog, Wpad, Wlog, 1, astride);
        } else {
            dim3 g(Npix / 128, M / 128, N);
            gemm_impl_k<2, 2, 1><<<g, TPB, 0, stream>>>(A, actb, nullptr, Cp,
                nullptr, M, K, Npix, 0, Cin, CPWlog, Wpad, Wlog, 1, astride);
        }
    };
    auto bn_t = [&](const float* src, const float* g_, const float* b_,
                    u16* dst, int C, int HWlog, int Wlog, int Wpad,
                    size_t ostride) {
        int HW = 1 << HWlog, NHW = N * HW;
        zero_k<<<1, TPB, 0, stream>>>(STATS, 256);
        dim3 gs(32, C);
        bn_stats_k<<<gs, TPB, 0, stream>>>(src, STATS, C, HWlog, NHW, 32);
        dim3 ga(HW / 64, C / 32, N);
        bn_apply_t_k<<<ga, TPB, 0, stream>>>(src, STATS, g_, b_, dst, C, HWlog,
                                             Wlog, Wpad, ostride,
                                             1.f / (float)NHW);
    };
    // offset conv (full batch) + channel-coalesced bilinear deform
    auto deform_stage = [&](const u16* woff, int C, int HWlog, int Wlog,
                            int H, int W, int Wpad, size_t astride,
                            int K, int CPWlog) {
        int HW = 1 << HWlog;
        gemm_off(woff, ACTB0, OFF, 2 * C, K, HW, C, CPWlog, Wpad, Wlog, astride);
        dim3 g(HW / 64, C / 32, N);
        deform_nhwc_k<<<g, TPB, 0, stream>>>(ACTB0, OFF, ACTB1, C, HWlog, Wlog,
                                             H, W, Wpad, astride);
    };

    const size_t AS1 = 540800;   // 130*130*32
    const size_t AS2 = 278784;   // 66*66*64
    const size_t AS3 = 557568;   // 66*66*128

    // stage-1 halos (both buffers, AS1 layout)
    halo_zero(ACTB0, 130, 130, 32, 5, AS1);
    halo_zero(ACTB1, 130, 130, 32, 5, AS1);

    // ---- conv11 (1->32, 128x128, s1, direct) + relu -> fp32 NCHW ----
    {
        dim3 g(8, 8, N * 8);
        conv3x3_k<1><<<g, TPB, 0, stream>>>(x, c11w, c11b, SCRATCH, N, 1, 128,
                                            128, 32, 128, 128, 1, 0);
    }
    bn_t(SCRATCH, bn11g, bn11b, ACTB0, 32, 14, 7, 130, AS1);

    // ---- off12 + deform12: ACTB0 -> ACTB1 (AS1) ----
    deform_stage(wo12, 32, 14, 7, 128, 128, 130, AS1, 288, 0);
    // ---- conv12 (32->64, s2) ----
    gemm(wc12, ACTB1, SCRATCH, c12b, 64, 288, 4096, 32, 0, 130, 6, 2, AS1);
    halo_zero(ACTB0, 66, 66, 64, 6, AS2);
    halo_zero(ACTB1, 66, 66, 64, 6, AS2);
    bn_t(SCRATCH, bn12g, bn12b, ACTB0, 64, 12, 6, 66, AS2);

    // ---- off21 + deform21: ACTB0 -> ACTB1 (AS2) ----
    deform_stage(wo21, 64, 12, 6, 64, 64, 66, AS2, 576, 1);
    // ---- conv21 (64->128, s1) ----
    gemm(wc21, ACTB1, SCRATCH, c21b, 128, 576, 4096, 64, 1, 66, 6, 1, AS2);
    halo_zero(ACTB0, 66, 66, 128, 7, AS3);
    halo_zero(ACTB1, 66, 66, 128, 7, AS3);
    bn_t(SCRATCH, bn21g, bn21b, ACTB0, 128, 12, 6, 66, AS3);

    // ---- off22 + deform22: ACTB0 -> ACTB1 (AS3) ----
    deform_stage(wo22, 128, 12, 6, 64, 64, 66, AS3, 1152, 2);
    // ---- conv22 (128->128, s2) ----
    gemm(wc22, ACTB1, SCRATCH, c22b, 128, 1152, 1024, 128, 2, 66, 5, 2, AS3);
    {   // bn22 in place (fp32 NCHW), GAP follows
        int HW = 1024, NHW = N * HW, total = N * 128 * HW;
        zero_k<<<1, TPB, 0, stream>>>(STATS, 256);
        dim3 gs(32, 128);
        bn_stats_k<<<gs, TPB, 0, stream>>>(SCRATCH, STATS, 128, 10, NHW, 32);
        bn_apply_k<<<(total + TPB - 1) / TPB, TPB, 0, stream>>>(
            SCRATCH, STATS, bn22g, bn22b, 127, 10, 1.f / (float)NHW, total);
    }

    // ---- GAP + FC + softmax ----
    gap_k<<<N * 128, 64, 0, stream>>>(SCRATCH, POOLED, 1024, 1.f / 1024.f);
    fc_softmax_k<<<N, 64, 0, stream>>>(POOLED, fcw, fcb, outp);
}